// Round 10
// baseline (127.509 us; speedup 1.0000x reference)
//
#include <hip/hip_runtime.h>
#include <math.h>

#define LL 2048
#define FF 352
#define BATCH 8
#define TOPK 84
#define FPB 2                   // f-rows per score block
#define BPB (FF / FPB)          // 176 blocks per batch
#define SBINS 4096              // k_score local hist bins (16 KB LDS -> 8 blk/CU)
#define SBINSCALE 512.0f        // bin = score * 512, range [0,8)
#define NBINS 8192              // k_final hist bins
#define BINSCALE 1024.0f        // k_final coarse bin = score * 1024
#define SUBBINS 8192            // k_final second-level bins within boundary bin
#define CAP 32768               // candidate buffer per batch (local top-84 union)
#define FCAP 1024               // k_final compact cap (C2 ~ 90)
#define NROWS (BATCH * 2 * FF)  // 5632
#define FL (FF * LL)            // 720896 scores per batch
#define CNTSTRIDE 64            // 256B between per-batch counters (no line sharing)

// ws layout (floats/ints share d_ws; regions disjoint)
#define OFF_Q 64                // 48 floats (query), ends 112
#define OFF_CNT 128             // 8 ints, stride 64 -> ends 640
#define OFF_PART 1024           // 5632 float4 (row partials), ends 23552
#define OFF_CS 32768            // 8*32768 floats (candidate scores), ends 294912
#define OFF_CI 294912           // 8*32768 ints  (candidate indices), ends 557056

// k_score local binning (only needs to be monotone + conservative)
__device__ __forceinline__ int sbin(float sv) {
    int bin = (int)(fmaxf(sv, 0.f) * SBINSCALE);
    return bin > SBINS - 1 ? SBINS - 1 : bin;
}
// k_final coarse/fine binning (value-based, independent of k_score's)
__device__ __forceinline__ int coarse_bin(float sv) {
    int bin = (int)(fmaxf(sv, 0.f) * BINSCALE);
    return bin > NBINS - 1 ? NBINS - 1 : bin;
}
__device__ __forceinline__ int fine_bin(float sv, int t) {
    float f = fmaxf(sv, 0.f) * BINSCALE - (float)t;
    int s = (int)(f * (float)SUBBINS);
    s = s < 0 ? 0 : s;
    return s > SUBBINS - 1 ? SUBBINS - 1 : s;
}

// Parallel threshold-find over LDS hist[NB]: bin t with
// suffix(t) >= K > suffix(t+1); sres[2]=t, sres[3]=count strictly above t.
// All 256 threads must call. Requires total count >= K.
// NB=8192 path (CW=32) is bit-identical to the round-5-verified version.
template<int NB>
__device__ __forceinline__ void find_thresh(const unsigned int* hist, int K,
                                            int tid, int lane, int wid,
                                            int* wtot, int* sres) {
    constexpr int CW = NB / 256;
    int csum = 0;
    #pragma unroll
    for (int k = 0; k < CW; ++k) csum += (int)hist[tid * CW + ((k + tid) & (CW - 1))];
    int sfx = csum;
    #pragma unroll
    for (int d = 1; d < 64; d <<= 1) {
        int o = __shfl_down(sfx, d);
        if (lane + d < 64) sfx += o;
    }
    if (lane == 0) wtot[wid] = sfx;
    __syncthreads();
    int hi = 0;
    #pragma unroll
    for (int w2 = 0; w2 < 4; ++w2) if (w2 > wid) hi += wtot[w2];
    int SC = sfx + hi;
    int SCn = SC - csum;
    if (SC >= K && SCn < K) { sres[0] = tid; sres[1] = SCn; }
    __syncthreads();
    int cstar = sres[0], aboveC = sres[1];
    if (tid < 64) {
        int hv = (tid < CW) ? (int)hist[cstar * CW + tid] : 0;
        int s2 = hv;
        #pragma unroll
        for (int d = 1; d < CW; d <<= 1) {
            int o = __shfl_down(s2, d);
            if (tid + d < 64) s2 += o;
        }
        int ge = aboveC + s2;
        int gt = ge - hv;
        if (tid < CW && ge >= K && gt < K) { sres[2] = cstar * CW + tid; sres[3] = gt; }
    }
    __syncthreads();
}

// One block per (b,ch,f) row: partial = (rowsum, x[0], x[1], x[L-1]).
// Block 0 also zeroes the per-batch candidate counters.
__global__ __launch_bounds__(256) void k_rowsum(const float* __restrict__ x,
                                                float* __restrict__ ws,
                                                int* __restrict__ wsi) {
    int r = blockIdx.x;              // (b*2+ch)*352 + f
    int tid = threadIdx.x;
    if (r == 0 && tid < 8) wsi[OFF_CNT + tid * CNTSTRIDE] = 0;
    const float4* rp = (const float4*)(x + (size_t)r * LL);
    float4 v0 = rp[tid];
    float4 v1 = rp[tid + 256];
    float s = v0.x + v0.y + v0.z + v0.w + v1.x + v1.y + v1.z + v1.w;
    for (int off = 32; off; off >>= 1) s += __shfl_down(s, off);
    __shared__ float red[4];
    int lane = tid & 63, wid = tid >> 6;
    if (lane == 0) red[wid] = s;
    __syncthreads();
    float* part = ws + OFF_PART + 4 * r;
    if (tid == 0) {
        part[0] = red[0] + red[1] + red[2] + red[3];
        part[1] = v0.x;
        part[2] = v0.y;
    }
    if (tid == 255) part[3] = v1.w;
}

// One block per (b, f-block of FPB=2): query prologue, register-stencil scores,
// 4096-bin LDS hist (17 KB -> 8 blocks/CU; 1408 blocks -> ~5.5/CU, ~69% occ),
// local top-84 threshold (parallel find), aggregated compaction.
__global__ __launch_bounds__(256) void k_score(const float* __restrict__ x,
                                               float* __restrict__ ws,
                                               int* __restrict__ wsi) {
    __shared__ unsigned int hist[SBINS];
    __shared__ float4 red0[4], red1[4];
    __shared__ float sq[6];
    __shared__ int wtot[4], sres[4];
    __shared__ int lcnt, lbase;
    int tid = threadIdx.x;
    int b = blockIdx.x / BPB, blk = blockIdx.x % BPB;
    int fb = blk * FPB;
    int lane = tid & 63, wid = tid >> 6;

    for (int k = 0; k < SBINS / 256; ++k) hist[tid + (k << 8)] = 0u;
    if (tid == 0) lcnt = 0;

    // ---- query prologue: reduce 704 partials for this batch ----
    float4 acc0 = {0.f, 0.f, 0.f, 0.f}, acc1 = {0.f, 0.f, 0.f, 0.f};
    const float4* part = (const float4*)(ws + OFF_PART) + b * 2 * FF;
    for (int i = tid; i < 2 * FF; i += 256) {
        float4 p = part[i];
        if (i < FF) { acc0.x += p.x; acc0.y += p.y; acc0.z += p.z; acc0.w += p.w; }
        else        { acc1.x += p.x; acc1.y += p.y; acc1.z += p.z; acc1.w += p.w; }
    }
    for (int off = 32; off; off >>= 1) {
        acc0.x += __shfl_down(acc0.x, off); acc0.y += __shfl_down(acc0.y, off);
        acc0.z += __shfl_down(acc0.z, off); acc0.w += __shfl_down(acc0.w, off);
        acc1.x += __shfl_down(acc1.x, off); acc1.y += __shfl_down(acc1.y, off);
        acc1.z += __shfl_down(acc1.z, off); acc1.w += __shfl_down(acc1.w, off);
    }
    if (lane == 0) { red0[wid] = acc0; red1[wid] = acc1; }
    __syncthreads();
    if (tid == 0) {
        float A0 = 0, B0 = 0, C0 = 0, D0 = 0, A1 = 0, B1 = 0, C1 = 0, D1 = 0;
        for (int w2 = 0; w2 < 4; ++w2) {
            A0 += red0[w2].x; B0 += red0[w2].y; C0 += red0[w2].z; D0 += red0[w2].w;
            A1 += red1[w2].x; B1 += red1[w2].y; C1 += red1[w2].z; D1 += red1[w2].w;
        }
        const float inv = 1.f / (float)FL;
        sq[0] = A0 * inv;
        sq[1] = A1 * inv;
        sq[2] = (A0 - B0 + D0) * inv;
        sq[3] = (A1 - B1 + D1) * inv;
        sq[4] = (A0 - B0 - C0 + 2.f * D0) * inv;
        sq[5] = (A1 - B1 - C1 + 2.f * D1) * inv;
        if (blk == 0) for (int e = 0; e < 6; ++e) ws[OFF_Q + b * 6 + e] = sq[e];
    }
    __syncthreads();
    float q0 = sq[0], q1 = sq[1], q2 = sq[2], q3 = sq[3], q4 = sq[4], q5 = sq[5];

    // ---- row pointers ----
    const float* r0p[FPB];
    const float* r1p[FPB];
    #pragma unroll
    for (int fr = 0; fr < FPB; ++fr) {
        r0p[fr] = x + ((size_t)(b * 2 + 0) * FF + fb + fr) * LL;
        r1p[fr] = x + ((size_t)(b * 2 + 1) * FF + fb + fr) * LL;
    }

    // ---- boundary prefetch: lane-63 stencil tails issued up front ----
    float pa4[FPB][2], pa5[FPB][2], pb4[FPB][2], pb5[FPB][2];
    if (lane == 63) {
        #pragma unroll
        for (int fr = 0; fr < FPB; ++fr) {
            #pragma unroll
            for (int h = 0; h < 2; ++h) {
                int l0 = (h << 10) + tid * 4;
                if (l0 != LL - 4) {
                    pa4[fr][h] = r0p[fr][l0 + 4]; pa5[fr][h] = r0p[fr][l0 + 5];
                    pb4[fr][h] = r1p[fr][l0 + 4]; pb5[fr][h] = r1p[fr][l0 + 5];
                }
            }
        }
    }

    // ---- pipelined scores: issue next loads before current compute ----
    float4 sreg[FPB][2];
    float4 u = *(const float4*)(r0p[0] + tid * 4);
    float4 v = *(const float4*)(r1p[0] + tid * 4);
    #pragma unroll
    for (int fr = 0; fr < FPB; ++fr) {
        #pragma unroll
        for (int h = 0; h < 2; ++h) {
            int l0 = (h << 10) + tid * 4;
            int nfr = (h == 1) ? fr + 1 : fr;
            int nh = (h == 1) ? 0 : 1;
            float4 un, vn;
            bool have_next = (nfr < FPB);
            if (have_next) {
                int ln = (nh << 10) + tid * 4;
                un = *(const float4*)(r0p[nfr] + ln);
                vn = *(const float4*)(r1p[nfr] + ln);
            }
            float a4 = __shfl_down(u.x, 1), a5 = __shfl_down(u.y, 1);
            float b4 = __shfl_down(v.x, 1), b5 = __shfl_down(v.y, 1);
            if (lane == 63) {
                if (l0 == LL - 4) { a4 = u.w; a5 = u.w; b4 = v.w; b5 = v.w; }
                else { a4 = pa4[fr][h]; a5 = pa5[fr][h];
                       b4 = pb4[fr][h]; b5 = pb5[fr][h]; }
            }
            float4 s;
            s.x = q0 * u.x + q1 * v.x + q2 * u.y + q3 * v.y + q4 * u.z + q5 * v.z;
            s.y = q0 * u.y + q1 * v.y + q2 * u.z + q3 * v.z + q4 * u.w + q5 * v.w;
            s.z = q0 * u.z + q1 * v.z + q2 * u.w + q3 * v.w + q4 * a4 + q5 * b4;
            s.w = q0 * u.w + q1 * v.w + q2 * a4 + q3 * b4 + q4 * a5 + q5 * b5;
            sreg[fr][h] = s;
            #pragma unroll
            for (int j = 0; j < 4; ++j) {
                float sv = j == 0 ? s.x : (j == 1 ? s.y : (j == 2 ? s.z : s.w));
                atomicAdd(&hist[sbin(sv)], 1u);
            }
            if (have_next) { u = un; v = vn; }
        }
    }
    __syncthreads();

    // ---- local threshold via parallel find (4096-bin) ----
    find_thresh<SBINS>(hist, TOPK, tid, lane, wid, wtot, sres);
    int t = sres[2];

    // ---- aggregated compaction: mask -> LDS offset -> 1 global atomic ----
    unsigned int kmask = 0u;
    #pragma unroll
    for (int fr = 0; fr < FPB; ++fr) {
        #pragma unroll
        for (int h = 0; h < 2; ++h) {
            float4 s = sreg[fr][h];
            #pragma unroll
            for (int j = 0; j < 4; ++j) {
                float sv = j == 0 ? s.x : (j == 1 ? s.y : (j == 2 ? s.z : s.w));
                if (sbin(sv) >= t) kmask |= 1u << ((fr << 3) + (h << 2) + j);
            }
        }
    }
    int cnt = __popc(kmask);
    int myoff = 0;
    if (cnt) myoff = atomicAdd(&lcnt, cnt);
    __syncthreads();
    if (tid == 0) lbase = atomicAdd(&wsi[OFF_CNT + b * CNTSTRIDE], lcnt);
    __syncthreads();
    int pos = lbase + myoff;
    #pragma unroll
    for (int fr = 0; fr < FPB; ++fr) {
        #pragma unroll
        for (int h = 0; h < 2; ++h) {
            float4 s = sreg[fr][h];
            int l0 = (h << 10) + tid * 4;
            int nb = (fb + fr) * LL + l0;
            #pragma unroll
            for (int j = 0; j < 4; ++j) {
                if (kmask & (1u << ((fr << 3) + (h << 2) + j))) {
                    float sv = j == 0 ? s.x : (j == 1 ? s.y : (j == 2 ? s.z : s.w));
                    if (pos < CAP) {
                        ws[OFF_CS + b * CAP + pos] = sv;
                        wsi[OFF_CI + b * CAP + pos] = nb + j;
                    }
                    ++pos;
                }
            }
        }
    }
}

// One block per batch: coarse hist -> t (parallel find); fine hist within t ->
// t2 (parallel find); compact (~90 elems) -> exact rank-select top-84 ->
// softmax (register-accumulated, wave-reduced) -> gather -> output.
__global__ __launch_bounds__(256) void k_final(const float* __restrict__ x,
                                               const float* __restrict__ wv,
                                               const float* __restrict__ ws,
                                               const int* __restrict__ wsi,
                                               float* __restrict__ out) {
    __shared__ union {
        unsigned int hist[NBINS];                    // 32 KB (stages 1-2)
        struct { float cs[FCAP]; int ci[FCAP]; } fin;// 8 KB (stages 3-4)
    } sh;
    __shared__ int wtot[4], sres[4];
    __shared__ int cnt2;
    __shared__ float redm[4];
    __shared__ float den;
    __shared__ float accsh[8];
    int tid = threadIdx.x;
    int b = blockIdx.x;
    int lane = tid & 63, wid = tid >> 6;

    int C = wsi[OFF_CNT + b * CNTSTRIDE];
    if (C > CAP) C = CAP;
    const float* gcs = ws + OFF_CS + b * CAP;
    const int* gci = wsi + OFF_CI + b * CAP;

    // ---- stage 1: coarse histogram (float4 scan), threshold t ----
    for (int k = 0; k < NBINS / 256; ++k) sh.hist[tid + (k << 8)] = 0u;
    __syncthreads();
    for (int p4 = tid * 4; p4 < C; p4 += 1024) {
        float4 s4 = *(const float4*)(gcs + p4);   // may overread <=3 into slack
        int lim = C - p4;
        atomicAdd(&sh.hist[coarse_bin(s4.x)], 1u);
        if (lim > 1) atomicAdd(&sh.hist[coarse_bin(s4.y)], 1u);
        if (lim > 2) atomicAdd(&sh.hist[coarse_bin(s4.z)], 1u);
        if (lim > 3) atomicAdd(&sh.hist[coarse_bin(s4.w)], 1u);
    }
    __syncthreads();
    find_thresh<NBINS>(sh.hist, TOPK, tid, lane, wid, wtot, sres);
    int t = sres[2];
    int above = sres[3];          // strictly above t (< TOPK)

    // ---- stage 2: fine histogram within bin t, sub-threshold t2 ----
    for (int k = 0; k < NBINS / 256; ++k) sh.hist[tid + (k << 8)] = 0u;
    __syncthreads();
    for (int p4 = tid * 4; p4 < C; p4 += 1024) {
        float4 s4 = *(const float4*)(gcs + p4);
        int lim = C - p4;
        #pragma unroll
        for (int j = 0; j < 4; ++j) {
            if (j >= lim) break;
            float sv = j == 0 ? s4.x : (j == 1 ? s4.y : (j == 2 ? s4.z : s4.w));
            if (coarse_bin(sv) == t) atomicAdd(&sh.hist[fine_bin(sv, t)], 1u);
        }
    }
    __syncthreads();
    find_thresh<NBINS>(sh.hist, TOPK - above, tid, lane, wid, wtot, sres);
    int t2 = sres[2];
    if (tid == 0) cnt2 = 0;
    __syncthreads();

    // ---- stage 3: compact survivors (~TOPK + ties) into LDS ----
    for (int p4 = tid * 4; p4 < C; p4 += 1024) {
        float4 s4 = *(const float4*)(gcs + p4);
        int4 i4 = *(const int4*)(gci + p4);
        int lim = C - p4;
        #pragma unroll
        for (int j = 0; j < 4; ++j) {
            if (j >= lim) break;
            float sv = j == 0 ? s4.x : (j == 1 ? s4.y : (j == 2 ? s4.z : s4.w));
            int iv = j == 0 ? i4.x : (j == 1 ? i4.y : (j == 2 ? i4.z : i4.w));
            int bin = coarse_bin(sv);
            bool keep = (bin > t) || (bin == t && fine_bin(sv, t) >= t2);
            if (keep) {
                int q = atomicAdd(&cnt2, 1);
                if (q < FCAP) { sh.fin.cs[q] = sv; sh.fin.ci[q] = iv; }
            }
        }
    }
    __syncthreads();
    int C2 = cnt2;
    if (C2 > FCAP) C2 = FCAP;

    if (tid < 8) accsh[tid] = 0.f;
    if (tid == 0) den = 0.f;
    __syncthreads();

    float m = -INFINITY;
    for (int p = tid; p < C2; p += 256) m = fmaxf(m, sh.fin.cs[p]);
    for (int off = 32; off; off >>= 1) m = fmaxf(m, __shfl_down(m, off));
    if (lane == 0) redm[wid] = m;
    __syncthreads();
    float smax = fmaxf(fmaxf(redm[0], redm[1]), fmaxf(redm[2], redm[3]));

    // ---- rank-select + softmax + gather, register-accumulated ----
    float g0 = 0.f, g1 = 0.f, g2 = 0.f, g3 = 0.f, g4 = 0.f, g5 = 0.f, dden = 0.f;
    for (int p = tid; p < C2; p += 256) {
        float s = sh.fin.cs[p];
        int idx = sh.fin.ci[p];
        int rank = 0;
        for (int j = 0; j < C2; ++j) {
            float sj = sh.fin.cs[j];
            int ij = sh.fin.ci[j];
            rank += (sj > s) || (sj == s && ij < idx);
        }
        if (rank < TOPK) {
            float pexp = expf(s - smax);
            dden += pexp;
            int f = idx >> 11, l = idx & (LL - 1);
            int l1 = l + 1 < LL ? l + 1 : LL - 1;
            int l2 = l + 2 < LL ? l + 2 : LL - 1;
            const float* r0 = x + ((size_t)(b * 2 + 0) * FF + f) * LL;
            const float* r1 = x + ((size_t)(b * 2 + 1) * FF + f) * LL;
            g0 += pexp * r0[l];
            g1 += pexp * r1[l];
            g2 += pexp * r0[l1];
            g3 += pexp * r1[l1];
            g4 += pexp * r0[l2];
            g5 += pexp * r1[l2];
        }
    }
    for (int off = 32; off; off >>= 1) {
        dden += __shfl_down(dden, off);
        g0 += __shfl_down(g0, off); g1 += __shfl_down(g1, off);
        g2 += __shfl_down(g2, off); g3 += __shfl_down(g3, off);
        g4 += __shfl_down(g4, off); g5 += __shfl_down(g5, off);
    }
    if (lane == 0) {
        atomicAdd(&den, dden);
        atomicAdd(&accsh[0], g0); atomicAdd(&accsh[1], g1);
        atomicAdd(&accsh[2], g2); atomicAdd(&accsh[3], g3);
        atomicAdd(&accsh[4], g4); atomicAdd(&accsh[5], g5);
    }
    __syncthreads();
    if (tid < 6) {
        float w = wv[0];
        float q = ws[OFF_Q + b * 6 + tid];
        out[b * 6 + tid] = (accsh[tid] / den) * w + q * (0.5f - w);
    }
}

extern "C" void kernel_launch(void* const* d_in, const int* in_sizes, int n_in,
                              void* d_out, int out_size, void* d_ws, size_t ws_size,
                              hipStream_t stream) {
    const float* x = (const float*)d_in[0];
    const float* w = (const float*)d_in[1];
    float* out = (float*)d_out;
    float* wsf = (float*)d_ws;
    int* wsi = (int*)d_ws;

    k_rowsum<<<NROWS, 256, 0, stream>>>(x, wsf, wsi);
    k_score<<<BATCH * BPB, 256, 0, stream>>>(x, wsf, wsi);
    k_final<<<BATCH, 256, 0, stream>>>(x, w, wsf, wsi, out);
}

// Round 11
// 112.300 us; speedup vs baseline: 1.1354x; 1.1354x over previous
//
#include <hip/hip_runtime.h>
#include <math.h>

#define LL 2048
#define FF 352
#define BATCH 8
#define TOPK 84
#define FPB 4                   // f-rows per score block
#define BPB (FF / FPB)          // 88 blocks per batch
#define NBINS 8192
#define BINSCALE 1024.0f        // bin = score * 1024, range [0,8)
#define SUBBINS 8192            // fine bins within the boundary bin
#define CAP 32768               // candidate buffer per batch
#define BCAP 2048               // k_final boundary list cap (expected ~420)
#define FINCAP 512              // k_final survivor cap (C2 ~ 90)
#define RPB 8                   // rows per k_rowsum block
#define NPART (NROWS / RPB)     // 704 partials, 44 per (b,ch)
#define NROWS (BATCH * 2 * FF)  // 5632
#define FL (FF * LL)            // 720896 scores per batch
#define CNTSTRIDE 64            // 256B between per-batch counters

// ws layout (floats/ints share d_ws; regions disjoint)
#define OFF_Q 64                // 48 floats (query), ends 112
#define OFF_CNT 128             // 8 ints, stride 64 -> ends 640
#define OFF_PART 1024           // 704 float4 (block partials), ends 3840
#define OFF_CS 32768            // 8*32768 floats (candidate scores)
#define OFF_CI 294912           // 8*32768 ints  (candidate indices)

__device__ __forceinline__ int coarse_bin(float sv) {
    int bin = (int)(fmaxf(sv, 0.f) * BINSCALE);
    return bin > NBINS - 1 ? NBINS - 1 : bin;
}
// fine sub-bin within coarse bin t; monotone in sv
__device__ __forceinline__ int fine_bin(float sv, int t) {
    float f = fmaxf(sv, 0.f) * BINSCALE - (float)t;
    int s = (int)(f * (float)SUBBINS);
    s = s < 0 ? 0 : s;
    return s > SUBBINS - 1 ? SUBBINS - 1 : s;
}

// Parallel threshold-find over LDS hist[NB]: bin t with
// suffix(t) >= K > suffix(t+1); sres[2]=t, sres[3]=count strictly above t.
// All 256 threads must call. Requires total count >= K. (Verified R5-R10.)
template<int NB>
__device__ __forceinline__ void find_thresh(const unsigned int* hist, int K,
                                            int tid, int lane, int wid,
                                            int* wtot, int* sres) {
    constexpr int CW = NB / 256;
    int csum = 0;
    #pragma unroll
    for (int k = 0; k < CW; ++k) csum += (int)hist[tid * CW + ((k + tid) & (CW - 1))];
    int sfx = csum;
    #pragma unroll
    for (int d = 1; d < 64; d <<= 1) {
        int o = __shfl_down(sfx, d);
        if (lane + d < 64) sfx += o;
    }
    if (lane == 0) wtot[wid] = sfx;
    __syncthreads();
    int hi = 0;
    #pragma unroll
    for (int w2 = 0; w2 < 4; ++w2) if (w2 > wid) hi += wtot[w2];
    int SC = sfx + hi;
    int SCn = SC - csum;
    if (SC >= K && SCn < K) { sres[0] = tid; sres[1] = SCn; }
    __syncthreads();
    int cstar = sres[0], aboveC = sres[1];
    if (tid < 64) {
        int hv = (tid < CW) ? (int)hist[cstar * CW + tid] : 0;
        int s2 = hv;
        #pragma unroll
        for (int d = 1; d < CW; d <<= 1) {
            int o = __shfl_down(s2, d);
            if (tid + d < 64) s2 += o;
        }
        int ge = aboveC + s2;
        int gt = ge - hv;
        if (tid < CW && ge >= K && gt < K) { sres[2] = cstar * CW + tid; sres[3] = gt; }
    }
    __syncthreads();
}

// One block per 8 rows of one (b,ch): partial = (sum, sum x[0], sum x[1],
// sum x[L-1]) over those 8 rows. 704 blocks -> 44 partials per (b,ch).
// Block 0 also zeroes the per-batch candidate counters.
__global__ __launch_bounds__(256) void k_rowsum(const float* __restrict__ x,
                                                float* __restrict__ ws,
                                                int* __restrict__ wsi) {
    int g = blockIdx.x;              // 0..703
    int tid = threadIdx.x;
    if (g == 0 && tid < 8) wsi[OFF_CNT + tid * CNTSTRIDE] = 0;
    int bc = g / 44, sub = g % 44;   // bc = b*2+ch
    int rr = tid >> 5, c = tid & 31; // row-in-block, chunk
    const float4* rp = (const float4*)(x + (size_t)(bc * FF + sub * RPB + rr) * LL);
    float s = 0.f, x0c = 0.f, x1c = 0.f, xlc = 0.f;
    #pragma unroll
    for (int k = 0; k < 16; ++k) {
        float4 v = rp[c + (k << 5)];
        s += v.x + v.y + v.z + v.w;
        if (k == 0 && c == 0) { x0c = v.x; x1c = v.y; }
        if (k == 15 && c == 31) xlc = v.w;
    }
    int lane = tid & 63, wid = tid >> 6;
    for (int off = 32; off; off >>= 1) {
        s += __shfl_down(s, off);
        x0c += __shfl_down(x0c, off);
        x1c += __shfl_down(x1c, off);
        xlc += __shfl_down(xlc, off);
    }
    __shared__ float4 red[4];
    if (lane == 0) red[wid] = make_float4(s, x0c, x1c, xlc);
    __syncthreads();
    if (tid == 0) {
        float4 p = make_float4(0.f, 0.f, 0.f, 0.f);
        for (int w2 = 0; w2 < 4; ++w2) {
            p.x += red[w2].x; p.y += red[w2].y; p.z += red[w2].z; p.w += red[w2].w;
        }
        ((float4*)(ws + OFF_PART))[g] = p;
    }
}

// One block per (b, f-block of 4): cheap query prologue (88 partials),
// pipelined register-stencil scores, 8192-bin LDS hist, local top-84
// threshold (parallel find), aggregated compaction.
__global__ __launch_bounds__(256, 4) void k_score(const float* __restrict__ x,
                                                  float* __restrict__ ws,
                                                  int* __restrict__ wsi) {
    __shared__ unsigned int hist[NBINS];
    __shared__ float4 red0[4], red1[4];
    __shared__ float sq[6];
    __shared__ int wtot[4], sres[4];
    __shared__ int lcnt, lbase;
    int tid = threadIdx.x;
    int b = blockIdx.x / BPB, blk = blockIdx.x % BPB;
    int fb = blk * FPB;
    int lane = tid & 63, wid = tid >> 6;

    for (int k = 0; k < NBINS / 256; ++k) hist[tid + (k << 8)] = 0u;
    if (tid == 0) lcnt = 0;

    // ---- query prologue: 88 pre-reduced partials for this batch ----
    float4 acc0 = {0.f, 0.f, 0.f, 0.f}, acc1 = {0.f, 0.f, 0.f, 0.f};
    if (tid < 88) {
        int ch = tid / 44, sb = tid % 44;
        float4 p = ((const float4*)(ws + OFF_PART))[(2 * b + ch) * 44 + sb];
        if (ch == 0) acc0 = p; else acc1 = p;
    }
    for (int off = 32; off; off >>= 1) {
        acc0.x += __shfl_down(acc0.x, off); acc0.y += __shfl_down(acc0.y, off);
        acc0.z += __shfl_down(acc0.z, off); acc0.w += __shfl_down(acc0.w, off);
        acc1.x += __shfl_down(acc1.x, off); acc1.y += __shfl_down(acc1.y, off);
        acc1.z += __shfl_down(acc1.z, off); acc1.w += __shfl_down(acc1.w, off);
    }
    if (lane == 0) { red0[wid] = acc0; red1[wid] = acc1; }
    __syncthreads();
    if (tid == 0) {
        float A0 = 0, B0 = 0, C0 = 0, D0 = 0, A1 = 0, B1 = 0, C1 = 0, D1 = 0;
        for (int w2 = 0; w2 < 4; ++w2) {
            A0 += red0[w2].x; B0 += red0[w2].y; C0 += red0[w2].z; D0 += red0[w2].w;
            A1 += red1[w2].x; B1 += red1[w2].y; C1 += red1[w2].z; D1 += red1[w2].w;
        }
        const float inv = 1.f / (float)FL;
        sq[0] = A0 * inv;
        sq[1] = A1 * inv;
        sq[2] = (A0 - B0 + D0) * inv;
        sq[3] = (A1 - B1 + D1) * inv;
        sq[4] = (A0 - B0 - C0 + 2.f * D0) * inv;
        sq[5] = (A1 - B1 - C1 + 2.f * D1) * inv;
        if (blk == 0) for (int e = 0; e < 6; ++e) ws[OFF_Q + b * 6 + e] = sq[e];
    }
    __syncthreads();
    float q0 = sq[0], q1 = sq[1], q2 = sq[2], q3 = sq[3], q4 = sq[4], q5 = sq[5];

    // ---- row pointers ----
    const float* r0p[FPB];
    const float* r1p[FPB];
    #pragma unroll
    for (int fr = 0; fr < FPB; ++fr) {
        r0p[fr] = x + ((size_t)(b * 2 + 0) * FF + fb + fr) * LL;
        r1p[fr] = x + ((size_t)(b * 2 + 1) * FF + fb + fr) * LL;
    }

    // ---- boundary prefetch: lane-63 stencil tails issued up front ----
    float pa4[FPB][2], pa5[FPB][2], pb4[FPB][2], pb5[FPB][2];
    if (lane == 63) {
        #pragma unroll
        for (int fr = 0; fr < FPB; ++fr) {
            #pragma unroll
            for (int h = 0; h < 2; ++h) {
                int l0 = (h << 10) + tid * 4;
                if (l0 != LL - 4) {
                    pa4[fr][h] = r0p[fr][l0 + 4]; pa5[fr][h] = r0p[fr][l0 + 5];
                    pb4[fr][h] = r1p[fr][l0 + 4]; pb5[fr][h] = r1p[fr][l0 + 5];
                }
            }
        }
    }

    // ---- pipelined scores: issue next loads before current compute ----
    float4 sreg[FPB][2];
    float4 u = *(const float4*)(r0p[0] + tid * 4);
    float4 v = *(const float4*)(r1p[0] + tid * 4);
    #pragma unroll
    for (int fr = 0; fr < FPB; ++fr) {
        #pragma unroll
        for (int h = 0; h < 2; ++h) {
            int l0 = (h << 10) + tid * 4;
            int nfr = (h == 1) ? fr + 1 : fr;
            int nh = (h == 1) ? 0 : 1;
            float4 un, vn;
            bool have_next = (nfr < FPB);
            if (have_next) {
                int ln = (nh << 10) + tid * 4;
                un = *(const float4*)(r0p[nfr] + ln);
                vn = *(const float4*)(r1p[nfr] + ln);
            }
            float a4 = __shfl_down(u.x, 1), a5 = __shfl_down(u.y, 1);
            float b4 = __shfl_down(v.x, 1), b5 = __shfl_down(v.y, 1);
            if (lane == 63) {
                if (l0 == LL - 4) { a4 = u.w; a5 = u.w; b4 = v.w; b5 = v.w; }
                else { a4 = pa4[fr][h]; a5 = pa5[fr][h];
                       b4 = pb4[fr][h]; b5 = pb5[fr][h]; }
            }
            float4 s;
            s.x = q0 * u.x + q1 * v.x + q2 * u.y + q3 * v.y + q4 * u.z + q5 * v.z;
            s.y = q0 * u.y + q1 * v.y + q2 * u.z + q3 * v.z + q4 * u.w + q5 * v.w;
            s.z = q0 * u.z + q1 * v.z + q2 * u.w + q3 * v.w + q4 * a4 + q5 * b4;
            s.w = q0 * u.w + q1 * v.w + q2 * a4 + q3 * b4 + q4 * a5 + q5 * b5;
            sreg[fr][h] = s;
            #pragma unroll
            for (int j = 0; j < 4; ++j) {
                float sv = j == 0 ? s.x : (j == 1 ? s.y : (j == 2 ? s.z : s.w));
                atomicAdd(&hist[coarse_bin(sv)], 1u);
            }
            if (have_next) { u = un; v = vn; }
        }
    }
    __syncthreads();

    // ---- local threshold via parallel find ----
    find_thresh<NBINS>(hist, TOPK, tid, lane, wid, wtot, sres);
    int t = sres[2];

    // ---- aggregated compaction: mask -> LDS offset -> 1 global atomic ----
    unsigned int kmask = 0u;
    #pragma unroll
    for (int fr = 0; fr < FPB; ++fr) {
        #pragma unroll
        for (int h = 0; h < 2; ++h) {
            float4 s = sreg[fr][h];
            #pragma unroll
            for (int j = 0; j < 4; ++j) {
                float sv = j == 0 ? s.x : (j == 1 ? s.y : (j == 2 ? s.z : s.w));
                if (coarse_bin(sv) >= t) kmask |= 1u << ((fr << 3) + (h << 2) + j);
            }
        }
    }
    int cnt = __popc(kmask);
    int myoff = 0;
    if (cnt) myoff = atomicAdd(&lcnt, cnt);
    __syncthreads();
    if (tid == 0) lbase = atomicAdd(&wsi[OFF_CNT + b * CNTSTRIDE], lcnt);
    __syncthreads();
    int pos = lbase + myoff;
    #pragma unroll
    for (int fr = 0; fr < FPB; ++fr) {
        #pragma unroll
        for (int h = 0; h < 2; ++h) {
            float4 s = sreg[fr][h];
            int l0 = (h << 10) + tid * 4;
            int nb = (fb + fr) * LL + l0;
            #pragma unroll
            for (int j = 0; j < 4; ++j) {
                if (kmask & (1u << ((fr << 3) + (h << 2) + j))) {
                    float sv = j == 0 ? s.x : (j == 1 ? s.y : (j == 2 ? s.z : s.w));
                    if (pos < CAP) {
                        ws[OFF_CS + b * CAP + pos] = sv;
                        wsi[OFF_CI + b * CAP + pos] = nb + j;
                    }
                    ++pos;
                }
            }
        }
    }
}

// One block per batch. Pass 1: coarse hist over C candidates (4 loads in
// flight) -> threshold t. Pass 2: all bin>=t candidates (~420) into LDS
// boundary list. Fine funnel + exact rank-select + softmax + gather in LDS.
__global__ __launch_bounds__(256) void k_final(const float* __restrict__ x,
                                               const float* __restrict__ wv,
                                               const float* __restrict__ ws,
                                               const int* __restrict__ wsi,
                                               float* __restrict__ out) {
    __shared__ unsigned int hist[NBINS];   // 32 KB
    __shared__ float bls[BCAP];            // 8 KB boundary scores
    __shared__ int bli[BCAP];              // 8 KB boundary indices
    __shared__ float fins[FINCAP];         // 2 KB survivors
    __shared__ int fini[FINCAP];           // 2 KB
    __shared__ int wtot[4], sres[4];
    __shared__ int bcnt, c2s;
    __shared__ float redm[4];
    __shared__ float den;
    __shared__ float accsh[8];
    int tid = threadIdx.x;
    int b = blockIdx.x;
    int lane = tid & 63, wid = tid >> 6;

    int C = wsi[OFF_CNT + b * CNTSTRIDE];
    if (C > CAP) C = CAP;
    const float* gcs = ws + OFF_CS + b * CAP;
    const int* gci = wsi + OFF_CI + b * CAP;

    // ---- pass 1: coarse histogram, 4 float4 loads in flight ----
    for (int k = 0; k < NBINS / 256; ++k) hist[tid + (k << 8)] = 0u;
    if (tid == 0) bcnt = 0;
    __syncthreads();
    for (int base = 0; base < C; base += 4096) {
        int j0 = base + tid * 4;
        float4 s0 = *(const float4*)(gcs + j0);
        float4 s1 = *(const float4*)(gcs + j0 + 1024);
        float4 s2 = *(const float4*)(gcs + j0 + 2048);
        float4 s3 = *(const float4*)(gcs + j0 + 3072);
        #pragma unroll
        for (int q = 0; q < 4; ++q) {
            float4 sq4 = q == 0 ? s0 : (q == 1 ? s1 : (q == 2 ? s2 : s3));
            int jq = j0 + q * 1024;
            #pragma unroll
            for (int j = 0; j < 4; ++j) {
                if (jq + j < C) {
                    float sv = j == 0 ? sq4.x : (j == 1 ? sq4.y : (j == 2 ? sq4.z : sq4.w));
                    atomicAdd(&hist[coarse_bin(sv)], 1u);
                }
            }
        }
    }
    __syncthreads();
    find_thresh<NBINS>(hist, TOPK, tid, lane, wid, wtot, sres);
    int t = sres[2];

    // ---- pass 2: compact bin>=t candidates into LDS boundary list ----
    for (int base = 0; base < C; base += 4096) {
        int j0 = base + tid * 4;
        float4 s0 = *(const float4*)(gcs + j0);
        float4 s1 = *(const float4*)(gcs + j0 + 1024);
        float4 s2 = *(const float4*)(gcs + j0 + 2048);
        float4 s3 = *(const float4*)(gcs + j0 + 3072);
        int4 i0 = *(const int4*)(gci + j0);
        int4 i1 = *(const int4*)(gci + j0 + 1024);
        int4 i2 = *(const int4*)(gci + j0 + 2048);
        int4 i3 = *(const int4*)(gci + j0 + 3072);
        #pragma unroll
        for (int q = 0; q < 4; ++q) {
            float4 sq4 = q == 0 ? s0 : (q == 1 ? s1 : (q == 2 ? s2 : s3));
            int4 iq4 = q == 0 ? i0 : (q == 1 ? i1 : (q == 2 ? i2 : i3));
            int jq = j0 + q * 1024;
            #pragma unroll
            for (int j = 0; j < 4; ++j) {
                if (jq + j < C) {
                    float sv = j == 0 ? sq4.x : (j == 1 ? sq4.y : (j == 2 ? sq4.z : sq4.w));
                    int iv = j == 0 ? iq4.x : (j == 1 ? iq4.y : (j == 2 ? iq4.z : iq4.w));
                    if (coarse_bin(sv) >= t) {
                        int p = atomicAdd(&bcnt, 1);
                        if (p < BCAP) { bls[p] = sv; bli[p] = iv; }
                    }
                }
            }
        }
    }
    __syncthreads();
    int nb = bcnt < BCAP ? bcnt : BCAP;

    // ---- fine funnel over boundary list: fkey = 8191 for bin>t else fine ----
    for (int k = 0; k < NBINS / 256; ++k) hist[tid + (k << 8)] = 0u;
    __syncthreads();
    for (int p = tid; p < nb; p += 256) {
        float sv = bls[p];
        int fk = coarse_bin(sv) > t ? SUBBINS - 1 : fine_bin(sv, t);
        atomicAdd(&hist[fk], 1u);
    }
    __syncthreads();
    find_thresh<NBINS>(hist, TOPK, tid, lane, wid, wtot, sres);
    int t2 = sres[2];
    if (tid == 0) c2s = 0;
    __syncthreads();
    for (int p = tid; p < nb; p += 256) {
        float sv = bls[p];
        int fk = coarse_bin(sv) > t ? SUBBINS - 1 : fine_bin(sv, t);
        if (fk >= t2) {
            int q = atomicAdd(&c2s, 1);
            if (q < FINCAP) { fins[q] = sv; fini[q] = bli[p]; }
        }
    }
    __syncthreads();
    int C2 = c2s < FINCAP ? c2s : FINCAP;

    if (tid < 8) accsh[tid] = 0.f;
    if (tid == 0) den = 0.f;
    __syncthreads();

    float m = -INFINITY;
    for (int p = tid; p < C2; p += 256) m = fmaxf(m, fins[p]);
    for (int off = 32; off; off >>= 1) m = fmaxf(m, __shfl_down(m, off));
    if (lane == 0) redm[wid] = m;
    __syncthreads();
    float smax = fmaxf(fmaxf(redm[0], redm[1]), fmaxf(redm[2], redm[3]));

    // ---- exact rank-select + softmax + gather, register-accumulated ----
    float g0 = 0.f, g1 = 0.f, g2 = 0.f, g3 = 0.f, g4 = 0.f, g5 = 0.f, dden = 0.f;
    for (int p = tid; p < C2; p += 256) {
        float s = fins[p];
        int idx = fini[p];
        int rank = 0;
        for (int j = 0; j < C2; ++j) {
            float sj = fins[j];
            int ij = fini[j];
            rank += (sj > s) || (sj == s && ij < idx);
        }
        if (rank < TOPK) {
            float pexp = expf(s - smax);
            dden += pexp;
            int f = idx >> 11, l = idx & (LL - 1);
            int l1 = l + 1 < LL ? l + 1 : LL - 1;
            int l2 = l + 2 < LL ? l + 2 : LL - 1;
            const float* r0 = x + ((size_t)(b * 2 + 0) * FF + f) * LL;
            const float* r1 = x + ((size_t)(b * 2 + 1) * FF + f) * LL;
            g0 += pexp * r0[l];
            g1 += pexp * r1[l];
            g2 += pexp * r0[l1];
            g3 += pexp * r1[l1];
            g4 += pexp * r0[l2];
            g5 += pexp * r1[l2];
        }
    }
    for (int off = 32; off; off >>= 1) {
        dden += __shfl_down(dden, off);
        g0 += __shfl_down(g0, off); g1 += __shfl_down(g1, off);
        g2 += __shfl_down(g2, off); g3 += __shfl_down(g3, off);
        g4 += __shfl_down(g4, off); g5 += __shfl_down(g5, off);
    }
    if (lane == 0) {
        atomicAdd(&den, dden);
        atomicAdd(&accsh[0], g0); atomicAdd(&accsh[1], g1);
        atomicAdd(&accsh[2], g2); atomicAdd(&accsh[3], g3);
        atomicAdd(&accsh[4], g4); atomicAdd(&accsh[5], g5);
    }
    __syncthreads();
    if (tid < 6) {
        float w = wv[0];
        float q = ws[OFF_Q + b * 6 + tid];
        out[b * 6 + tid] = (accsh[tid] / den) * w + q * (0.5f - w);
    }
}

extern "C" void kernel_launch(void* const* d_in, const int* in_sizes, int n_in,
                              void* d_out, int out_size, void* d_ws, size_t ws_size,
                              hipStream_t stream) {
    const float* x = (const float*)d_in[0];
    const float* w = (const float*)d_in[1];
    float* out = (float*)d_out;
    float* wsf = (float*)d_ws;
    int* wsi = (int*)d_ws;

    k_rowsum<<<NPART, 256, 0, stream>>>(x, wsf, wsi);
    k_score<<<BATCH * BPB, 256, 0, stream>>>(x, wsf, wsi);
    k_final<<<BATCH, 256, 0, stream>>>(x, w, wsf, wsi, out);
}